// Round 5
// baseline (735.498 us; speedup 1.0000x reference)
//
#include <hip/hip_runtime.h>
#include <hip/hip_bf16.h>
#include <stdint.h>
#include <math.h>

#define DM 1024
#define DH 2048
#define NB 4
#define SL 4096
#define MT (NB*SL)   // 16384 rows
#define LC 256       // scan chunk length
#define NC (SL/LC)   // 16 chunks per channel

typedef __bf16 bf16;
typedef __attribute__((ext_vector_type(8))) __bf16 bf16x8;
typedef __attribute__((ext_vector_type(4))) __bf16 bf16x4;
typedef __attribute__((ext_vector_type(4))) float f32x4;

// ===========================================================================
// Fused fp32 -> bf16 sanitizing convert for all 9 tensors in one launch.
// ===========================================================================
struct CvtArgs {
  const float* in[9];
  bf16* out[9];
  int cum[10];   // cumulative vec4 counts, cum[0]=0
};

__global__ void cvt_all(CvtArgs a) {
  const int total4 = a.cum[9];
  for (int i = blockIdx.x * 256 + threadIdx.x; i < total4; i += gridDim.x * 256) {
    int s = 0;
#pragma unroll 8
    while (i >= a.cum[s + 1]) ++s;
    const int j = i - a.cum[s];
    f32x4 v = *(const f32x4*)(a.in[s] + 4 * (size_t)j);
    bf16x4 o;
#pragma unroll
    for (int k = 0; k < 4; ++k) {
      float x = v[k];
      x = (x == x) ? fminf(fmaxf(x, -65504.f), 65504.f) : 0.f;
      o[k] = (bf16)x;
    }
    *(bf16x4*)(a.out[s] + 4 * (size_t)j) = o;
  }
}

__device__ __forceinline__ void g2lds(const bf16* g, bf16* l) {
  __builtin_amdgcn_global_load_lds((const __attribute__((address_space(1))) void*)g,
                                   (__attribute__((address_space(3))) void*)l,
                                   16, 0, 0);
}

// ===========================================================================
// Round-5: 256x256 8-wave deep-pipelined GEMM (T2+T3+T4+T5 port).
// Round-4 PMC: LDS diet bought nothing (dual 141.9 vs 142.0us, MfmaUtil 42%)
// => the 2-barrier vmcnt(0)-drain K-loop is the ceiling (~900-970 TF, m97
// structure). Proven escape: 256^2 schedule with COUNTED vmcnt.
//
// Geometry: BM=BN=256, BK=64, 512 thr = 8 waves (2M x 4N); per-wave output
// 128x64 = acc[8][4] f32x4 (128 VGPR). LDS 128KB: 2 bufs x (A 32KB + B 32KB).
// Tiles stored as 32 chunks of 8 rows x 64k, lane l stages global k-chunk
// (l&7)^(l>>3) at linear slot l (pre-swizzled source, linear LDS dest);
// ds_read reads slot kc^(row&7) -- proven 0-conflict.
//
// Schedule per K-tile k (4 phases; quadrant = row-half RH x col-half CH):
//   P0(RH0,CH0) reads A-h0,B-h0   stage: Ah1(k+1)->other buf   end: vmcnt(6)
//   P1(RH0,CH1) reads A-h0,B-h1   stage: Bh1(k+1)->other buf
//   P2(RH1,CH0) reads A-h1,B-h0   stage: Ah0(k+2)->THIS buf (A-h0 freed @P1)
//   P3(RH1,CH1) reads A-h1,B-h1   stage: Bh0(k+2)->THIS buf (B-h0 freed @P2)
//                                                             end: vmcnt(8)
// A-half h = row chunks {h*8..h*8+7, 16+h*8..}; B-half h = chunks with
// bit2==h (cols wn*64+{0..31} vs {32..63}). Each stage = 16 chunks = 8 waves
// x 2 calls x 1KB. Every half is staged >=1 phase after its last reader's
// trailing barrier and lands >=4 phases before first use:
//   vmcnt(6) @endP0 leaves {Ah0(k+2),Bh0(k+2),Ah1(k+1)} in flight =>
//     Bh1(k),Ah1(k) landed for P1/P2/P3;
//   vmcnt(8) @endP3 leaves this iter's 4 stages in flight =>
//     Ah0(k+1),Bh0(k+1) landed for next P0.
// Raw s_barrier (NO __syncthreads => no vmcnt(0) drain inside the loop);
// per-wave vmcnt + barrier joins cover cross-wave staging. ds_reads cannot
// hoist past the memory-clobber vmcnt asm that guarantees their data.
// setprio(1) around each 16-MFMA cluster (T5; needs phase role-split).
// Concat-K (K2>0): tile t pulls from (A1,W1) if t<K1/64 else (A2,W2).
// MODE 0: out_bf16 = acc (+bias1 (+bias2 if K2))
// MODE 1: out_f32  = acc + extra_bf16[off]          (final residual)
// MODE 2: out_bf16 = extra_bf16[off] * silu(acc)    (z-gate)
// ===========================================================================
#define G256_PHASE(RH, CH, STAGE, VM)                                         \
  {                                                                           \
    bf16x8 af[4][2], bfr[2][2];                                               \
    _Pragma("unroll")                                                         \
    for (int rf = 0; rf < 4; ++rf) {                                          \
      const int ra = wm*128 + ((RH)*4+rf)*16 + mrow;                          \
      _Pragma("unroll")                                                       \
      for (int ks = 0; ks < 2; ++ks)                                          \
        af[rf][ks] = *(const bf16x8*)&lA[(ra*8 + ((ks*4+kg)^(ra&7)))*8];      \
    }                                                                         \
    _Pragma("unroll")                                                         \
    for (int cf = 0; cf < 2; ++cf) {                                          \
      const int rb = wn*64 + ((CH)*2+cf)*16 + mrow;                           \
      _Pragma("unroll")                                                       \
      for (int ks = 0; ks < 2; ++ks)                                          \
        bfr[cf][ks] = *(const bf16x8*)&lB[(rb*8 + ((ks*4+kg)^(rb&7)))*8];     \
    }                                                                         \
    STAGE;                                                                    \
    __builtin_amdgcn_s_barrier();                                             \
    __builtin_amdgcn_s_setprio(1);                                            \
    _Pragma("unroll")                                                         \
    for (int rf = 0; rf < 4; ++rf)                                            \
      _Pragma("unroll")                                                       \
      for (int cf = 0; cf < 2; ++cf)                                          \
        _Pragma("unroll")                                                     \
        for (int ks = 0; ks < 2; ++ks)                                        \
          acc[(RH)*4+rf][(CH)*2+cf] = __builtin_amdgcn_mfma_f32_16x16x32_bf16(\
              af[rf][ks], bfr[cf][ks], acc[(RH)*4+rf][(CH)*2+cf], 0, 0, 0);   \
    __builtin_amdgcn_s_setprio(0);                                            \
    VM;                                                                       \
    __builtin_amdgcn_s_barrier();                                             \
  }

template<int MODE, bool HAS_BIAS, int N, int K1, int K2>
__global__ __launch_bounds__(512, 1)
void gemm256(const bf16* __restrict__ A1, const bf16* __restrict__ W1,
             const float* __restrict__ bias1,
             const bf16* __restrict__ A2, const bf16* __restrict__ W2,
             const float* __restrict__ bias2,
             const void* __restrict__ extra, void* __restrict__ outp) {
  constexpr int NT1 = K1 / 64;
  constexpr int NT  = (K1 + K2) / 64;
  __shared__ __align__(16) char pool[131072];
  bf16* const bA0 = (bf16*)pool;
  bf16* const bA1 = bA0 + 16384;
  bf16* const bB0 = bA0 + 32768;
  bf16* const bB1 = bA0 + 49152;

  const int tid  = threadIdx.x;
  const int wave = tid >> 6;
  const int lane = tid & 63;
  const int wm = wave >> 2, wn = wave & 3;
  const int r_in = lane >> 3;
  const int kc_l = (lane & 7) ^ r_in;
  const int mrow = lane & 15;
  const int kg   = lane >> 4;

  // XCD swizzle (bijective: total blocks % 8 == 0)
  constexpr int NBN = N / 256;
  const int nbm8 = (int)(gridDim.y >> 3);
  const int id   = (int)(blockIdx.y * NBN + blockIdx.x);
  const int xcd  = id & 7;
  const unsigned jj = (unsigned)id >> 3;
  const int bm   = xcd * nbm8 + (int)(jj / (unsigned)NBN);
  const int bn   = (int)(jj & (NBN - 1));
  const int arow0 = bm * 256;
  const int brow0 = bn * 256;

  // stage one A-half (h): chunks {h*8+(0..7), 16+h*8+(0..7)}; 2 calls/thread
  auto stageA = [&](int h, int t, bf16* dst) {
#pragma unroll
    for (int j = 0; j < 2; ++j) {
      const int idx = wave * 2 + j;
      const int c   = h * 8 + (idx & 7) + ((idx & 8) << 1);
      const int grow = arow0 + c * 8 + r_in;
      const bf16* src;
      if constexpr (K2 > 0) {
        if (t < NT1) src = A1 + (size_t)grow * K1 + t * 64 + kc_l * 8;
        else         src = A2 + (size_t)grow * K2 + (t - NT1) * 64 + kc_l * 8;
      } else {
        src = A1 + (size_t)grow * K1 + t * 64 + kc_l * 8;
      }
      g2lds(src, dst + c * 512);
    }
  };
  // stage one B-half (h): chunks with bit2==h: {(idx>>2)*8 + h*4 + (idx&3)}
  auto stageB = [&](int h, int t, bf16* dst) {
#pragma unroll
    for (int j = 0; j < 2; ++j) {
      const int idx = wave * 2 + j;
      const int c   = ((idx >> 2) << 3) + h * 4 + (idx & 3);
      const int grow = brow0 + c * 8 + r_in;
      const bf16* src;
      if constexpr (K2 > 0) {
        if (t < NT1) src = W1 + (size_t)grow * K1 + t * 64 + kc_l * 8;
        else         src = W2 + (size_t)grow * K2 + (t - NT1) * 64 + kc_l * 8;
      } else {
        src = W1 + (size_t)grow * K1 + t * 64 + kc_l * 8;
      }
      g2lds(src, dst + c * 512);
    }
  };

  f32x4 acc[8][4];
#pragma unroll
  for (int i = 0; i < 8; ++i)
#pragma unroll
    for (int j = 0; j < 4; ++j) acc[i][j] = {0.f, 0.f, 0.f, 0.f};

  // Prologue: tile0 all 4 halves + tile1 Ah0,Bh0 (12 ops/thread).
  stageA(0, 0, bA0); stageB(0, 0, bB0);
  stageA(1, 0, bA0); stageB(1, 0, bB0);
  stageA(0, 1, bA1); stageB(0, 1, bB1);
  asm volatile("s_waitcnt vmcnt(8)" ::: "memory");   // tile0 Ah0,Bh0 landed
  __builtin_amdgcn_s_barrier();

#pragma unroll 1
  for (int k = 0; k < NT; ++k) {
    const int kb = k & 1;
    bf16* const lA = kb ? bA1 : bA0;
    bf16* const lB = kb ? bB1 : bB0;
    bf16* const oA = kb ? bA0 : bA1;
    bf16* const oB = kb ? bB0 : bB1;
    G256_PHASE(0, 0, { if (k + 1 < NT) stageA(1, k + 1, oA); },
               asm volatile("s_waitcnt vmcnt(6)" ::: "memory"))
    G256_PHASE(0, 1, { if (k + 1 < NT) stageB(1, k + 1, oB); }, )
    G256_PHASE(1, 0, { if (k + 2 < NT) stageA(0, k + 2, lA); }, )
    G256_PHASE(1, 1, { if (k + 2 < NT) stageB(0, k + 2, lB); },
               asm volatile("s_waitcnt vmcnt(8)" ::: "memory"))
  }

  // Epilogue: LDS restage -> coalesced stores. 4 passes of 32 rows;
  // per-wave 32x68 f32 slot (8704B x 8 waves = 69632 <= 128K pool).
  __syncthreads();   // full drain (incl. vmcnt) before LDS reuse
  float* eps = (float*)pool + wave * 2176;
  const int rr  = lane >> 3;
  const int cc  = (lane & 7) * 8;
  const int gcol0 = bn * 256 + wn * 64 + cc;
  f32x4 bv0 = {0.f, 0.f, 0.f, 0.f}, bv1 = {0.f, 0.f, 0.f, 0.f};
  if constexpr (HAS_BIAS) {
    bv0 = *(const f32x4*)(bias1 + gcol0);
    bv1 = *(const f32x4*)(bias1 + gcol0 + 4);
  }
  if constexpr (K2 > 0) {
    bv0 += *(const f32x4*)(bias2 + gcol0);
    bv1 += *(const f32x4*)(bias2 + gcol0 + 4);
  }

#pragma unroll
  for (int p = 0; p < 4; ++p) {
#pragma unroll
    for (int rfp = 0; rfp < 2; ++rfp) {
      const int rf = p * 2 + rfp;
#pragma unroll
      for (int cf = 0; cf < 4; ++cf)
#pragma unroll
        for (int r = 0; r < 4; ++r)
          eps[(rfp * 16 + kg * 4 + r) * 68 + cf * 16 + mrow] = acc[rf][cf][r];
    }
#pragma unroll
    for (int rnd = 0; rnd < 4; ++rnd) {
      const int lr   = rnd * 8 + rr;
      const int grow = bm * 256 + wm * 128 + p * 32 + lr;
      f32x4 v0 = *(const f32x4*)&eps[lr * 68 + cc];
      f32x4 v1 = *(const f32x4*)&eps[lr * 68 + cc + 4];
      const size_t off = (size_t)grow * N + gcol0;
      float vv[8];
#pragma unroll
      for (int k = 0; k < 4; ++k) { vv[k] = v0[k] + bv0[k]; vv[4 + k] = v1[k] + bv1[k]; }

      float res[8];
      if constexpr (MODE == 0) {
#pragma unroll
        for (int k = 0; k < 8; ++k) res[k] = vv[k];
      } else if constexpr (MODE == 1) {
        bf16x8 e = *(const bf16x8*)((const bf16*)extra + off);
#pragma unroll
        for (int k = 0; k < 8; ++k) res[k] = vv[k] + (float)e[k];
      } else {  // MODE 2
        bf16x8 g = *(const bf16x8*)((const bf16*)extra + off);
#pragma unroll
        for (int k = 0; k < 8; ++k) {
          const float v = vv[k];
          res[k] = (float)g[k] * (v / (1.f + __expf(-v)));
        }
      }

      if constexpr (MODE == 1) {
        f32x4 o0, o1;
#pragma unroll
        for (int k = 0; k < 4; ++k) { o0[k] = res[k]; o1[k] = res[4 + k]; }
        *(f32x4*)((float*)outp + off)     = o0;
        *(f32x4*)((float*)outp + off + 4) = o1;
      } else {
        bf16x8 o;
#pragma unroll
        for (int k = 0; k < 8; ++k) o[k] = (bf16)res[k];
        *(bf16x8*)((bf16*)outp + off) = o;
      }
    }
  }
}

// ===========================================================================
// Dual GEMM (unchanged from round 4): nla = softplus(A.dlw^T+b1)*(A.Aw^T+b2).
// 128x128 tile, shares A-tile across two accumulators. LDS 49152.
// ===========================================================================
template<int N, int K>
__global__ __launch_bounds__(256, 2)
void gemm_dual(const bf16* __restrict__ A, const bf16* __restrict__ W1,
               const bf16* __restrict__ W2, const float* __restrict__ b1,
               const float* __restrict__ b2, bf16* __restrict__ outp) {
  __shared__ __align__(16) char pool[49152];
  bf16* lds_a  = (bf16*)pool;
  bf16* lds_b1 = (bf16*)(pool + 16384);
  bf16* lds_b2 = (bf16*)(pool + 32768);

  const int tid  = threadIdx.x;
  const int wave = tid >> 6;
  const int lane = tid & 63;
  const int wm = wave >> 1, wn = wave & 1;

  constexpr int NBN = N / 128;
  const int nbm8 = (int)(gridDim.y >> 3);
  const int id   = (int)(blockIdx.y * NBN + blockIdx.x);
  const int xcd  = id & 7;
  const unsigned jj = (unsigned)id >> 3;
  const int bm   = xcd * nbm8 + (int)(jj / (unsigned)NBN);
  const int bn   = (int)(jj & (NBN - 1));
  const size_t arow0 = (size_t)bm * 128;
  const size_t brow0 = (size_t)bn * 128;

  const int r_in = lane >> 3;
  const int kc_l = (lane & 7) ^ r_in;
  const int mrow = lane & 15;
  const int kg   = lane >> 4;

  f32x4 acc1[4][4], acc2[4][4];
#pragma unroll
  for (int i = 0; i < 4; ++i)
#pragma unroll
    for (int j = 0; j < 4; ++j) { acc1[i][j] = {0.f,0.f,0.f,0.f}; acc2[i][j] = {0.f,0.f,0.f,0.f}; }

  const bf16* pa[4]; const bf16* pb1[4]; const bf16* pb2[4];
#pragma unroll
  for (int iss = 0; iss < 4; ++iss) {
    const int row = (iss * 4 + wave) * 8 + r_in;
    pa[iss]  = A  + (arow0 + row) * (size_t)K + kc_l * 8;
    pb1[iss] = W1 + (brow0 + row) * (size_t)K + kc_l * 8;
    pb2[iss] = W2 + (brow0 + row) * (size_t)K + kc_l * 8;
  }

#pragma unroll 1
  for (int k0 = 0; k0 < K; k0 += 64) {
    __syncthreads();
#pragma unroll
    for (int iss = 0; iss < 4; ++iss) {
      const int chunk = iss * 4 + wave;
      g2lds(pa[iss],  &lds_a [chunk * 512]); pa[iss]  += 64;
      g2lds(pb1[iss], &lds_b1[chunk * 512]); pb1[iss] += 64;
      g2lds(pb2[iss], &lds_b2[chunk * 512]); pb2[iss] += 64;
    }
    __syncthreads();
#pragma unroll
    for (int ks = 0; ks < 2; ++ks) {
      bf16x8 af[4], b1f[4], b2f[4];
#pragma unroll
      for (int t = 0; t < 4; ++t) {
        const int ra = wm * 64 + t * 16 + mrow;
        const int sa = ra * 8 + ((ks * 4 + kg) ^ (ra & 7));
        af[t] = *(const bf16x8*)&lds_a[sa * 8];
        const int rb = wn * 64 + t * 16 + mrow;
        const int sb = rb * 8 + ((ks * 4 + kg) ^ (rb & 7));
        b1f[t] = *(const bf16x8*)&lds_b1[sb * 8];
        b2f[t] = *(const bf16x8*)&lds_b2[sb * 8];
      }
#pragma unroll
      for (int i = 0; i < 4; ++i)
#pragma unroll
        for (int j = 0; j < 4; ++j) {
          acc1[i][j] = __builtin_amdgcn_mfma_f32_16x16x32_bf16(af[i], b1f[j], acc1[i][j], 0, 0, 0);
          acc2[i][j] = __builtin_amdgcn_mfma_f32_16x16x32_bf16(af[i], b2f[j], acc2[i][j], 0, 0, 0);
        }
    }
  }

  __syncthreads();
  float* eps1 = (float*)pool + wave * 2176;
  float* eps2 = eps1 + 1088;
  const int rr  = lane >> 3;
  const int cc  = (lane & 7) * 8;
  const int gcol0 = bn * 128 + wn * 64 + cc;
  f32x4 b1v0 = *(const f32x4*)(b1 + gcol0);
  f32x4 b1v1 = *(const f32x4*)(b1 + gcol0 + 4);
  f32x4 b2v0 = *(const f32x4*)(b2 + gcol0);
  f32x4 b2v1 = *(const f32x4*)(b2 + gcol0 + 4);

#pragma unroll
  for (int i = 0; i < 4; ++i) {
#pragma unroll
    for (int j = 0; j < 4; ++j)
#pragma unroll
      for (int r = 0; r < 4; ++r) {
        const int lr = kg * 4 + r;
        eps1[lr * 68 + j * 16 + mrow] = acc1[i][j][r];
        eps2[lr * 68 + j * 16 + mrow] = acc2[i][j][r];
      }
#pragma unroll
    for (int rnd = 0; rnd < 2; ++rnd) {
      const int lr   = rnd * 8 + rr;
      const int grow = bm * 128 + wm * 64 + i * 16 + lr;
      f32x4 u0  = *(const f32x4*)&eps1[lr * 68 + cc];
      f32x4 u1  = *(const f32x4*)&eps1[lr * 68 + cc + 4];
      f32x4 w0  = *(const f32x4*)&eps2[lr * 68 + cc];
      f32x4 w1v = *(const f32x4*)&eps2[lr * 68 + cc + 4];
      const size_t off = (size_t)grow * N + gcol0;
      bf16x8 o;
#pragma unroll
      for (int k = 0; k < 8; ++k) {
        const float dv = (k < 4 ? u0[k] + b1v0[k] : u1[k - 4] + b1v1[k - 4]);
        const float av = (k < 4 ? w0[k] + b2v0[k] : w1v[k - 4] + b2v1[k - 4]);
        const float sp = (dv > 15.f) ? dv : __logf(1.f + __expf(dv));
        o[k] = (bf16)(sp * av);
      }
      *(bf16x8*)(outp + off) = o;
    }
  }
}

// ===========================================================================
// depthwise conv1d(k=3, pad=1 along L, per-batch) + bias + silu. 8 d's/thread.
// ===========================================================================
__global__ void conv_silu_kernel(const bf16* __restrict__ t1, const float* __restrict__ cw,
                                 const float* __restrict__ cb, bf16* __restrict__ xc) {
  const int gid  = blockIdx.x * 256 + threadIdx.x;
  const int dgrp = gid & (DM / 8 - 1);
  const int bl   = gid >> 7;
  const int l    = bl & (SL - 1);
  const int d0   = dgrp * 8;
  const bf16* p  = t1 + (size_t)bl * DM + d0;
  bf16x8 cc = *(const bf16x8*)p;
  bf16x8 lf, rt;
#pragma unroll
  for (int j = 0; j < 8; ++j) { lf[j] = (bf16)0.f; rt[j] = (bf16)0.f; }
  if (l > 0)      lf = *(const bf16x8*)(p - DM);
  if (l < SL - 1) rt = *(const bf16x8*)(p + DM);
  bf16x8 o;
#pragma unroll
  for (int j = 0; j < 8; ++j) {
    const int d = d0 + j;
    float y = cw[d * 3 + 0] * (float)lf[j] + cw[d * 3 + 1] * (float)cc[j]
            + cw[d * 3 + 2] * (float)rt[j] + cb[d];
    y = y / (1.f + __expf(-y));
    o[j] = (bf16)y;
  }
  *(bf16x8*)(xc + (size_t)bl * DM + d0) = o;
}

// ===========================================================================
// Parallel scan over L, 3 phases, chunked (LC=256, NC=16).
// ===========================================================================
__global__ void scan_phase1(bf16* nla_sl, const bf16* __restrict__ bx,
                            float* __restrict__ Lp_tot, float* __restrict__ T_tot) {
  const int g  = blockIdx.x * 256 + threadIdx.x;
  const int ch = g & (DH - 1);
  const int rc = g >> 11;
  const int b  = rc & (NB - 1);
  const int c  = rc >> 2;
  const int bc = b * DH + ch;
  size_t off = ((size_t)(b * SL + c * LC)) * DH + ch;
  float lp = 0.f, S = 0.f;
#pragma unroll 8
  for (int l = 0; l < LC; ++l, off += DH) {
    const float a = (float)nla_sl[off];
    const float x = (float)bx[off];
    lp += a;
    const float e = __expf(-fminf(fmaxf(lp, -80.f), 80.f));
    S = fmaf(x, e, S);
    nla_sl[off] = (bf16)S;
  }
  Lp_tot[c * (NB * DH) + bc] = lp;
  T_tot [c * (NB * DH) + bc] = S;
}

__global__ void scan_phase2(const float* __restrict__ Lp_tot, const float* __restrict__ T_tot,
                            float* __restrict__ lpoff, float* __restrict__ Soff) {
  const int bc = blockIdx.x * 256 + threadIdx.x;
  float lp = 0.f, S = 0.f;
#pragma unroll
  for (int c = 0; c < NC; ++c) {
    lpoff[c * (NB * DH) + bc] = lp;
    Soff [c * (NB * DH) + bc] = S;
    const float e = __expf(-fminf(fmaxf(lp, -80.f), 80.f));
    S  = fmaf(e, T_tot[c * (NB * DH) + bc], S);
    lp += Lp_tot[c * (NB * DH) + bc];
  }
}

__global__ void scan_phase3(const bf16* __restrict__ S_local, bf16* __restrict__ h,
                            const float* __restrict__ lpoff, const float* __restrict__ Soff) {
  const int g  = blockIdx.x * 256 + threadIdx.x;
  const int ch = g & (DH - 1);
  const int rc = g >> 11;
  const int b  = rc & (NB - 1);
  const int c  = rc >> 2;
  const int bc = b * DH + ch;
  const float lo = lpoff[c * (NB * DH) + bc];
  const float so = Soff [c * (NB * DH) + bc];
  const float es = __expf(-fminf(fmaxf(lo, -80.f), 80.f));
  size_t off = ((size_t)(b * SL + c * LC)) * DH + ch;
#pragma unroll 8
  for (int l = 0; l < LC; ++l, off += DH) {
    h[off] = (bf16)fmaf(es, (float)S_local[off], so);
  }
}

// ===========================================================================
// Workspace (max live 186 MB), offsets in MB:
//  [  0.. 24): bf16 weights (persistent)
//  [ 24.. 56): xc
//  [ 56..120): t1 [56,88) / xbf [88,120) -> bxh (Bx, then h) ; z [56,88)
//  [120..184): nla (scan in-place) -> ssm [120,152)
//  [184..186): scan totals
// ===========================================================================
extern "C" void kernel_launch(void* const* d_in, const int* in_sizes, int n_in,
                              void* d_out, int out_size, void* d_ws, size_t ws_size,
                              hipStream_t stream) {
  const float* x    = (const float*)d_in[0];
  const float* w1   = (const float*)d_in[1];
  const float* w2   = (const float*)d_in[2];
  const float* w3   = (const float*)d_in[3];
  const float* cw   = (const float*)d_in[4];
  const float* cb   = (const float*)d_in[5];
  const float* A_w  = (const float*)d_in[6];
  const float* A_b  = (const float*)d_in[7];
  const float* B_w  = (const float*)d_in[8];
  const float* B_b  = (const float*)d_in[9];
  const float* C_w  = (const float*)d_in[10];
  const float* C_b  = (const float*)d_in[11];
  const float* D_w  = (const float*)d_in[12];
  const float* D_b  = (const float*)d_in[13];
  const float* dl_w = (const float*)d_in[14];
  const float* dl_b = (const float*)d_in[15];

  const size_t MB = 1048576u;
  char* ws = (char*)d_ws;
  bf16* w1b  = (bf16*)(ws + 0*MB);
  bf16* w2b  = (bf16*)(ws + 2*MB);
  bf16* w3b  = (bf16*)(ws + 4*MB);
  bf16* Dwb  = (bf16*)(ws + 6*MB);
  bf16* Awb  = (bf16*)(ws + 8*MB);
  bf16* Bwb  = (bf16*)(ws + 12*MB);
  bf16* dlwb = (bf16*)(ws + 16*MB);
  bf16* Cwb  = (bf16*)(ws + 20*MB);
  bf16* xc   = (bf16*)(ws + 24*MB);
  bf16* t1   = (bf16*)(ws + 56*MB);
  bf16* z    = t1;
  bf16* xbf  = (bf16*)(ws + 88*MB);
  bf16* bxh  = (bf16*)(ws + 56*MB);   // 64 MB: Bx, then h (phase3 in-place)
  bf16* nla  = (bf16*)(ws + 120*MB);  // 64 MB; S_local in-place
  bf16* ssm  = (bf16*)(ws + 120*MB);  // 32 MB, after nla dies (post-scan3)
  float* Lp_tot = (float*)(ws + 184*MB);
  float* T_tot  = (float*)(ws + 184*MB + 524288u);
  float* lpoff  = (float*)(ws + 185*MB);
  float* Soff   = (float*)(ws + 185*MB + 524288u);
  float* outp = (float*)d_out;

  dim3 blk(256);
  dim3 blk512(512);
  dim3 g1_256(DM / 256, MT / 256);   // (4, 64)
  dim3 g2_256(DH / 256, MT / 256);   // (8, 64)
  dim3 g2(DH / 128, MT / 128);       // dual: (16, 128)

  // --- convert all inputs to bf16 (sanitizing), single launch ---
  {
    CvtArgs a;
    const float* ins[9]  = {x, w1, w2, w3, D_w, A_w, B_w, dl_w, C_w};
    bf16*        outs[9] = {xbf, w1b, w2b, w3b, Dwb, Awb, Bwb, dlwb, Cwb};
    const int    n4s[9]  = {MT*DM/4, DM*DM/4, DM*DM/4, DM*DM/4, DM*DM/4,
                            DH*DM/4, DH*DM/4, DH*DM/4, DM*DH/4};
    int c = 0;
    a.cum[0] = 0;
    for (int i = 0; i < 9; ++i) { a.in[i] = ins[i]; a.out[i] = outs[i]; c += n4s[i]; a.cum[i+1] = c; }
    cvt_all<<<2048, blk, 0, stream>>>(a);
  }

  // --- pipeline ---
  gemm256<0,false,DM,DM,0><<<g1_256, blk512, 0, stream>>>(xbf, w1b, nullptr,
      nullptr, nullptr, nullptr, nullptr, t1);
  conv_silu_kernel<<<MT * DM / 8 / 256, blk, 0, stream>>>(t1, cw, cb, xc);
  gemm_dual<DH,DM><<<g2, blk, 0, stream>>>(xc, dlwb, Awb, dl_b, A_b, nla);
  gemm256<0,true ,DH,DM,0><<<g2_256, blk512, 0, stream>>>(xc, Bwb, B_b,
      nullptr, nullptr, nullptr, nullptr, bxh);
  scan_phase1<<<MT * NC * DH / SL / 256, blk, 0, stream>>>(nla, bxh, Lp_tot, T_tot);
  scan_phase2<<<NB * DH / 256, blk, 0, stream>>>(Lp_tot, T_tot, lpoff, Soff);
  scan_phase3<<<MT * NC * DH / SL / 256, blk, 0, stream>>>(nla, bxh, lpoff, Soff);
  // ssm = C.h + D.x + C_b + D_b  (concatenated-K fused pass)
  gemm256<0,true ,DM,DH,DM><<<g1_256, blk512, 0, stream>>>(bxh, Cwb, C_b,
      xc, Dwb, D_b, nullptr, ssm);
  gemm256<2,false,DM,DM,0><<<g1_256, blk512, 0, stream>>>(ssm, w2b, nullptr,
      nullptr, nullptr, nullptr, ssm, z);
  gemm256<1,false,DM,DM,0><<<g1_256, blk512, 0, stream>>>(z,   w3b, nullptr,
      nullptr, nullptr, nullptr, ssm, outp);
}

// Round 6
// 659.044 us; speedup vs baseline: 1.1160x; 1.1160x over previous
//
#include <hip/hip_runtime.h>
#include <hip/hip_bf16.h>
#include <stdint.h>
#include <math.h>

#define DM 1024
#define DH 2048
#define NB 4
#define SL 4096
#define MT (NB*SL)   // 16384 rows
#define LC 256       // scan chunk length
#define NC (SL/LC)   // 16 chunks per channel

typedef __bf16 bf16;
typedef __attribute__((ext_vector_type(8))) __bf16 bf16x8;
typedef __attribute__((ext_vector_type(4))) __bf16 bf16x4;
typedef __attribute__((ext_vector_type(4))) float f32x4;

// ===========================================================================
// Fused fp32 -> bf16 sanitizing convert for all 9 tensors in one launch.
// ===========================================================================
struct CvtArgs {
  const float* in[9];
  bf16* out[9];
  int cum[10];   // cumulative vec4 counts, cum[0]=0
};

__global__ void cvt_all(CvtArgs a) {
  const int total4 = a.cum[9];
  for (int i = blockIdx.x * 256 + threadIdx.x; i < total4; i += gridDim.x * 256) {
    int s = 0;
#pragma unroll 8
    while (i >= a.cum[s + 1]) ++s;
    const int j = i - a.cum[s];
    f32x4 v = *(const f32x4*)(a.in[s] + 4 * (size_t)j);
    bf16x4 o;
#pragma unroll
    for (int k = 0; k < 4; ++k) {
      float x = v[k];
      x = (x == x) ? fminf(fmaxf(x, -65504.f), 65504.f) : 0.f;
      o[k] = (bf16)x;
    }
    *(bf16x4*)(a.out[s] + 4 * (size_t)j) = o;
  }
}

__device__ __forceinline__ void g2lds(const bf16* g, bf16* l) {
  __builtin_amdgcn_global_load_lds((const __attribute__((address_space(1))) void*)g,
                                   (__attribute__((address_space(3))) void*)l,
                                   16, 0, 0);
}

// ===========================================================================
// Round-6: fix the 256x256 pipelined GEMM's LDS-read volume.
// Round-5 regression root-cause: each of the 4 phases re-read BOTH its
// A-row-half and B-col-half fragments => 48 ds_read_b128/K-tile/wave;
// per CU (1 block, 8 waves) that's ~4600 LDS-pipe cycles vs ~2060 MFMA
// cycles -- the loop was LDS-read-bound. m201's verified template reads
// 24 ("4 or 8 ds_read" per phase) by HOLDING operands in registers.
// New snake order, register-held fragments:
//   P0 q(RH0,CH0): read A-h0(8)+B-h0(4); stage Ah1(k+1)->oA; end vmcnt(6)
//   P1 q(RH0,CH1): read B-h1(4), A held; stage Bh1(k+1)->oB
//   P2 q(RH1,CH1): read A-h1(8), B-h1 held; stage Ah0(k+2)->lA
//   P3 q(RH1,CH0): NO reads (A-h1, B-h0 held); stage Bh0(k+2)->lB; vmcnt(8)
// 24 reads/K-tile ~= 2300 LDS cyc ~= MFMA 2060 cyc. Waits re-derived, same
// counts as round 5 (vmcnt is per-wave; every wave waits its own count
// BEFORE the trailing barrier => collective guarantee). All overwrites now
// land >=2 barriers after their last reader's lgkm-completed read.
// Everything else identical to round 5.
// MODE 0: out_bf16 = acc (+bias1 (+bias2 if K2))
// MODE 1: out_f32  = acc + extra_bf16[off]          (final residual)
// MODE 2: out_bf16 = extra_bf16[off] * silu(acc)    (z-gate)
// ===========================================================================
template<int MODE, bool HAS_BIAS, int N, int K1, int K2>
__global__ __launch_bounds__(512, 1)
void gemm256(const bf16* __restrict__ A1, const bf16* __restrict__ W1,
             const float* __restrict__ bias1,
             const bf16* __restrict__ A2, const bf16* __restrict__ W2,
             const float* __restrict__ bias2,
             const void* __restrict__ extra, void* __restrict__ outp) {
  constexpr int NT1 = K1 / 64;
  constexpr int NT  = (K1 + K2) / 64;
  __shared__ __align__(16) char pool[131072];
  bf16* const bA0 = (bf16*)pool;
  bf16* const bA1 = bA0 + 16384;
  bf16* const bB0 = bA0 + 32768;
  bf16* const bB1 = bA0 + 49152;

  const int tid  = threadIdx.x;
  const int wave = tid >> 6;
  const int lane = tid & 63;
  const int wm = wave >> 2, wn = wave & 3;
  const int r_in = lane >> 3;
  const int kc_l = (lane & 7) ^ r_in;
  const int mrow = lane & 15;
  const int kg   = lane >> 4;

  // XCD swizzle (bijective: total blocks % 8 == 0)
  constexpr int NBN = N / 256;
  const int nbm8 = (int)(gridDim.y >> 3);
  const int id   = (int)(blockIdx.y * NBN + blockIdx.x);
  const int xcd  = id & 7;
  const unsigned jj = (unsigned)id >> 3;
  const int bm   = xcd * nbm8 + (int)(jj / (unsigned)NBN);
  const int bn   = (int)(jj & (NBN - 1));
  const int arow0 = bm * 256;
  const int brow0 = bn * 256;

  // stage one A-half (h): chunks {h*8+(0..7), 16+h*8+(0..7)}; 2 calls/thread
  auto stageA = [&](int h, int t, bf16* dst) {
#pragma unroll
    for (int j = 0; j < 2; ++j) {
      const int idx = wave * 2 + j;
      const int c   = h * 8 + (idx & 7) + ((idx & 8) << 1);
      const int grow = arow0 + c * 8 + r_in;
      const bf16* src;
      if constexpr (K2 > 0) {
        if (t < NT1) src = A1 + (size_t)grow * K1 + t * 64 + kc_l * 8;
        else         src = A2 + (size_t)grow * K2 + (t - NT1) * 64 + kc_l * 8;
      } else {
        src = A1 + (size_t)grow * K1 + t * 64 + kc_l * 8;
      }
      g2lds(src, dst + c * 512);
    }
  };
  // stage one B-half (h): chunks {(idx>>2)*8 + h*4 + (idx&3)}
  auto stageB = [&](int h, int t, bf16* dst) {
#pragma unroll
    for (int j = 0; j < 2; ++j) {
      const int idx = wave * 2 + j;
      const int c   = ((idx >> 2) << 3) + h * 4 + (idx & 3);
      const int grow = brow0 + c * 8 + r_in;
      const bf16* src;
      if constexpr (K2 > 0) {
        if (t < NT1) src = W1 + (size_t)grow * K1 + t * 64 + kc_l * 8;
        else         src = W2 + (size_t)grow * K2 + (t - NT1) * 64 + kc_l * 8;
      } else {
        src = W1 + (size_t)grow * K1 + t * 64 + kc_l * 8;
      }
      g2lds(src, dst + c * 512);
    }
  };

  f32x4 acc[8][4];
#pragma unroll
  for (int i = 0; i < 8; ++i)
#pragma unroll
    for (int j = 0; j < 4; ++j) acc[i][j] = {0.f, 0.f, 0.f, 0.f};

  // Prologue: tile0 all 4 halves -> buf0 + tile1 Ah0,Bh0 -> buf1.
  stageA(0, 0, bA0); stageB(0, 0, bB0);
  stageA(1, 0, bA0); stageB(1, 0, bB0);
  stageA(0, 1, bA1); stageB(0, 1, bB1);
  asm volatile("s_waitcnt vmcnt(8)" ::: "memory");   // tile0 Ah0,Bh0 landed
  __builtin_amdgcn_s_barrier();

#pragma unroll 1
  for (int k = 0; k < NT; ++k) {
    const int kb = k & 1;
    bf16* const lA = kb ? bA1 : bA0;
    bf16* const lB = kb ? bB1 : bB0;
    bf16* const oA = kb ? bA0 : bA1;
    bf16* const oB = kb ? bB0 : bB1;
    bf16x8 aF[4][2], bF0[2][2], bF1[2][2];

    // ---- P0 q(0,0): read A-h0 + B-h0; stage Ah1(k+1)->oA ----
#pragma unroll
    for (int rf = 0; rf < 4; ++rf) {
      const int ra = wm * 128 + rf * 16 + mrow;
#pragma unroll
      for (int ks = 0; ks < 2; ++ks)
        aF[rf][ks] = *(const bf16x8*)&lA[(ra * 8 + ((ks * 4 + kg) ^ (ra & 7))) * 8];
    }
#pragma unroll
    for (int cf = 0; cf < 2; ++cf) {
      const int rb = wn * 64 + cf * 16 + mrow;
#pragma unroll
      for (int ks = 0; ks < 2; ++ks)
        bF0[cf][ks] = *(const bf16x8*)&lB[(rb * 8 + ((ks * 4 + kg) ^ (rb & 7))) * 8];
    }
    if (k + 1 < NT) stageA(1, k + 1, oA);
    __builtin_amdgcn_s_barrier();
    __builtin_amdgcn_s_setprio(1);
#pragma unroll
    for (int rf = 0; rf < 4; ++rf)
#pragma unroll
      for (int cf = 0; cf < 2; ++cf)
#pragma unroll
        for (int ks = 0; ks < 2; ++ks)
          acc[rf][cf] = __builtin_amdgcn_mfma_f32_16x16x32_bf16(
              aF[rf][ks], bF0[cf][ks], acc[rf][cf], 0, 0, 0);
    __builtin_amdgcn_s_setprio(0);
    asm volatile("s_waitcnt vmcnt(6)" ::: "memory");
    __builtin_amdgcn_s_barrier();

    // ---- P1 q(0,1): read B-h1 (A held); stage Bh1(k+1)->oB ----
#pragma unroll
    for (int cf = 0; cf < 2; ++cf) {
      const int rb = wn * 64 + 32 + cf * 16 + mrow;
#pragma unroll
      for (int ks = 0; ks < 2; ++ks)
        bF1[cf][ks] = *(const bf16x8*)&lB[(rb * 8 + ((ks * 4 + kg) ^ (rb & 7))) * 8];
    }
    if (k + 1 < NT) stageB(1, k + 1, oB);
    __builtin_amdgcn_s_barrier();
    __builtin_amdgcn_s_setprio(1);
#pragma unroll
    for (int rf = 0; rf < 4; ++rf)
#pragma unroll
      for (int cf = 0; cf < 2; ++cf)
#pragma unroll
        for (int ks = 0; ks < 2; ++ks)
          acc[rf][2 + cf] = __builtin_amdgcn_mfma_f32_16x16x32_bf16(
              aF[rf][ks], bF1[cf][ks], acc[rf][2 + cf], 0, 0, 0);
    __builtin_amdgcn_s_setprio(0);
    __builtin_amdgcn_s_barrier();

    // ---- P2 q(1,1): read A-h1 (B-h1 held); stage Ah0(k+2)->lA ----
#pragma unroll
    for (int rf = 0; rf < 4; ++rf) {
      const int ra = wm * 128 + 64 + rf * 16 + mrow;
#pragma unroll
      for (int ks = 0; ks < 2; ++ks)
        aF[rf][ks] = *(const bf16x8*)&lA[(ra * 8 + ((ks * 4 + kg) ^ (ra & 7))) * 8];
    }
    if (k + 2 < NT) stageA(0, k + 2, lA);
    __builtin_amdgcn_s_barrier();
    __builtin_amdgcn_s_setprio(1);
#pragma unroll
    for (int rf = 0; rf < 4; ++rf)
#pragma unroll
      for (int cf = 0; cf < 2; ++cf)
#pragma unroll
        for (int ks = 0; ks < 2; ++ks)
          acc[4 + rf][2 + cf] = __builtin_amdgcn_mfma_f32_16x16x32_bf16(
              aF[rf][ks], bF1[cf][ks], acc[4 + rf][2 + cf], 0, 0, 0);
    __builtin_amdgcn_s_setprio(0);
    __builtin_amdgcn_s_barrier();

    // ---- P3 q(1,0): NO reads (A-h1, B-h0 held); stage Bh0(k+2)->lB ----
    if (k + 2 < NT) stageB(0, k + 2, lB);
    __builtin_amdgcn_s_barrier();
    __builtin_amdgcn_s_setprio(1);
#pragma unroll
    for (int rf = 0; rf < 4; ++rf)
#pragma unroll
      for (int cf = 0; cf < 2; ++cf)
#pragma unroll
        for (int ks = 0; ks < 2; ++ks)
          acc[4 + rf][cf] = __builtin_amdgcn_mfma_f32_16x16x32_bf16(
              aF[rf][ks], bF0[cf][ks], acc[4 + rf][cf], 0, 0, 0);
    __builtin_amdgcn_s_setprio(0);
    asm volatile("s_waitcnt vmcnt(8)" ::: "memory");
    __builtin_amdgcn_s_barrier();
  }

  // Epilogue: LDS restage -> coalesced stores. 4 passes of 32 rows;
  // per-wave 32x68 f32 slot (8704B x 8 waves = 69632 <= 128K pool).
  __syncthreads();   // full drain (incl. vmcnt) before LDS reuse
  float* eps = (float*)pool + wave * 2176;
  const int rr  = lane >> 3;
  const int cc  = (lane & 7) * 8;
  const int gcol0 = bn * 256 + wn * 64 + cc;
  f32x4 bv0 = {0.f, 0.f, 0.f, 0.f}, bv1 = {0.f, 0.f, 0.f, 0.f};
  if constexpr (HAS_BIAS) {
    bv0 = *(const f32x4*)(bias1 + gcol0);
    bv1 = *(const f32x4*)(bias1 + gcol0 + 4);
  }
  if constexpr (K2 > 0) {
    bv0 += *(const f32x4*)(bias2 + gcol0);
    bv1 += *(const f32x4*)(bias2 + gcol0 + 4);
  }

#pragma unroll
  for (int p = 0; p < 4; ++p) {
#pragma unroll
    for (int rfp = 0; rfp < 2; ++rfp) {
      const int rf = p * 2 + rfp;
#pragma unroll
      for (int cf = 0; cf < 4; ++cf)
#pragma unroll
        for (int r = 0; r < 4; ++r)
          eps[(rfp * 16 + kg * 4 + r) * 68 + cf * 16 + mrow] = acc[rf][cf][r];
    }
#pragma unroll
    for (int rnd = 0; rnd < 4; ++rnd) {
      const int lr   = rnd * 8 + rr;
      const int grow = bm * 256 + wm * 128 + p * 32 + lr;
      f32x4 v0 = *(const f32x4*)&eps[lr * 68 + cc];
      f32x4 v1 = *(const f32x4*)&eps[lr * 68 + cc + 4];
      const size_t off = (size_t)grow * N + gcol0;
      float vv[8];
#pragma unroll
      for (int k = 0; k < 4; ++k) { vv[k] = v0[k] + bv0[k]; vv[4 + k] = v1[k] + bv1[k]; }

      float res[8];
      if constexpr (MODE == 0) {
#pragma unroll
        for (int k = 0; k < 8; ++k) res[k] = vv[k];
      } else if constexpr (MODE == 1) {
        bf16x8 e = *(const bf16x8*)((const bf16*)extra + off);
#pragma unroll
        for (int k = 0; k < 8; ++k) res[k] = vv[k] + (float)e[k];
      } else {  // MODE 2
        bf16x8 g = *(const bf16x8*)((const bf16*)extra + off);
#pragma unroll
        for (int k = 0; k < 8; ++k) {
          const float v = vv[k];
          res[k] = (float)g[k] * (v / (1.f + __expf(-v)));
        }
      }

      if constexpr (MODE == 1) {
        f32x4 o0, o1;
#pragma unroll
        for (int k = 0; k < 4; ++k) { o0[k] = res[k]; o1[k] = res[4 + k]; }
        *(f32x4*)((float*)outp + off)     = o0;
        *(f32x4*)((float*)outp + off + 4) = o1;
      } else {
        bf16x8 o;
#pragma unroll
        for (int k = 0; k < 8; ++k) o[k] = (bf16)res[k];
        *(bf16x8*)((bf16*)outp + off) = o;
      }
    }
  }
}

// ===========================================================================
// Dual GEMM (unchanged): nla = softplus(A.dlw^T+b1)*(A.Aw^T+b2).
// 128x128 tile, shares A-tile across two accumulators. LDS 49152.
// ===========================================================================
template<int N, int K>
__global__ __launch_bounds__(256, 2)
void gemm_dual(const bf16* __restrict__ A, const bf16* __restrict__ W1,
               const bf16* __restrict__ W2, const float* __restrict__ b1,
               const float* __restrict__ b2, bf16* __restrict__ outp) {
  __shared__ __align__(16) char pool[49152];
  bf16* lds_a  = (bf16*)pool;
  bf16* lds_b1 = (bf16*)(pool + 16384);
  bf16* lds_b2 = (bf16*)(pool + 32768);

  const int tid  = threadIdx.x;
  const int wave = tid >> 6;
  const int lane = tid & 63;
  const int wm = wave >> 1, wn = wave & 1;

  constexpr int NBN = N / 128;
  const int nbm8 = (int)(gridDim.y >> 3);
  const int id   = (int)(blockIdx.y * NBN + blockIdx.x);
  const int xcd  = id & 7;
  const unsigned jj = (unsigned)id >> 3;
  const int bm   = xcd * nbm8 + (int)(jj / (unsigned)NBN);
  const int bn   = (int)(jj & (NBN - 1));
  const size_t arow0 = (size_t)bm * 128;
  const size_t brow0 = (size_t)bn * 128;

  const int r_in = lane >> 3;
  const int kc_l = (lane & 7) ^ r_in;
  const int mrow = lane & 15;
  const int kg   = lane >> 4;

  f32x4 acc1[4][4], acc2[4][4];
#pragma unroll
  for (int i = 0; i < 4; ++i)
#pragma unroll
    for (int j = 0; j < 4; ++j) { acc1[i][j] = {0.f,0.f,0.f,0.f}; acc2[i][j] = {0.f,0.f,0.f,0.f}; }

  const bf16* pa[4]; const bf16* pb1[4]; const bf16* pb2[4];
#pragma unroll
  for (int iss = 0; iss < 4; ++iss) {
    const int row = (iss * 4 + wave) * 8 + r_in;
    pa[iss]  = A  + (arow0 + row) * (size_t)K + kc_l * 8;
    pb1[iss] = W1 + (brow0 + row) * (size_t)K + kc_l * 8;
    pb2[iss] = W2 + (brow0 + row) * (size_t)K + kc_l * 8;
  }

#pragma unroll 1
  for (int k0 = 0; k0 < K; k0 += 64) {
    __syncthreads();
#pragma unroll
    for (int iss = 0; iss < 4; ++iss) {
      const int chunk = iss * 4 + wave;
      g2lds(pa[iss],  &lds_a [chunk * 512]); pa[iss]  += 64;
      g2lds(pb1[iss], &lds_b1[chunk * 512]); pb1[iss] += 64;
      g2lds(pb2[iss], &lds_b2[chunk * 512]); pb2[iss] += 64;
    }
    __syncthreads();
#pragma unroll
    for (int ks = 0; ks < 2; ++ks) {
      bf16x8 af[4], b1f[4], b2f[4];
#pragma unroll
      for (int t = 0; t < 4; ++t) {
        const int ra = wm * 64 + t * 16 + mrow;
        const int sa = ra * 8 + ((ks * 4 + kg) ^ (ra & 7));
        af[t] = *(const bf16x8*)&lds_a[sa * 8];
        const int rb = wn * 64 + t * 16 + mrow;
        const int sb = rb * 8 + ((ks * 4 + kg) ^ (rb & 7));
        b1f[t] = *(const bf16x8*)&lds_b1[sb * 8];
        b2f[t] = *(const bf16x8*)&lds_b2[sb * 8];
      }
#pragma unroll
      for (int i = 0; i < 4; ++i)
#pragma unroll
        for (int j = 0; j < 4; ++j) {
          acc1[i][j] = __builtin_amdgcn_mfma_f32_16x16x32_bf16(af[i], b1f[j], acc1[i][j], 0, 0, 0);
          acc2[i][j] = __builtin_amdgcn_mfma_f32_16x16x32_bf16(af[i], b2f[j], acc2[i][j], 0, 0, 0);
        }
    }
  }

  __syncthreads();
  float* eps1 = (float*)pool + wave * 2176;
  float* eps2 = eps1 + 1088;
  const int rr  = lane >> 3;
  const int cc  = (lane & 7) * 8;
  const int gcol0 = bn * 128 + wn * 64 + cc;
  f32x4 b1v0 = *(const f32x4*)(b1 + gcol0);
  f32x4 b1v1 = *(const f32x4*)(b1 + gcol0 + 4);
  f32x4 b2v0 = *(const f32x4*)(b2 + gcol0);
  f32x4 b2v1 = *(const f32x4*)(b2 + gcol0 + 4);

#pragma unroll
  for (int i = 0; i < 4; ++i) {
#pragma unroll
    for (int j = 0; j < 4; ++j)
#pragma unroll
      for (int r = 0; r < 4; ++r) {
        const int lr = kg * 4 + r;
        eps1[lr * 68 + j * 16 + mrow] = acc1[i][j][r];
        eps2[lr * 68 + j * 16 + mrow] = acc2[i][j][r];
      }
#pragma unroll
    for (int rnd = 0; rnd < 2; ++rnd) {
      const int lr   = rnd * 8 + rr;
      const int grow = bm * 128 + wm * 64 + i * 16 + lr;
      f32x4 u0  = *(const f32x4*)&eps1[lr * 68 + cc];
      f32x4 u1  = *(const f32x4*)&eps1[lr * 68 + cc + 4];
      f32x4 w0  = *(const f32x4*)&eps2[lr * 68 + cc];
      f32x4 w1v = *(const f32x4*)&eps2[lr * 68 + cc + 4];
      const size_t off = (size_t)grow * N + gcol0;
      bf16x8 o;
#pragma unroll
      for (int k = 0; k < 8; ++k) {
        const float dv = (k < 4 ? u0[k] + b1v0[k] : u1[k - 4] + b1v1[k - 4]);
        const float av = (k < 4 ? w0[k] + b2v0[k] : w1v[k - 4] + b2v1[k - 4]);
        const float sp = (dv > 15.f) ? dv : __logf(1.f + __expf(dv));
        o[k] = (bf16)(sp * av);
      }
      *(bf16x8*)(outp + off) = o;
    }
  }
}

// ===========================================================================
// depthwise conv1d(k=3, pad=1 along L, per-batch) + bias + silu. 8 d's/thread.
// ===========================================================================
__global__ void conv_silu_kernel(const bf16* __restrict__ t1, const float* __restrict__ cw,
                                 const float* __restrict__ cb, bf16* __restrict__ xc) {
  const int gid  = blockIdx.x * 256 + threadIdx.x;
  const int dgrp = gid & (DM / 8 - 1);
  const int bl   = gid >> 7;
  const int l    = bl & (SL - 1);
  const int d0   = dgrp * 8;
  const bf16* p  = t1 + (size_t)bl * DM + d0;
  bf16x8 cc = *(const bf16x8*)p;
  bf16x8 lf, rt;
#pragma unroll
  for (int j = 0; j < 8; ++j) { lf[j] = (bf16)0.f; rt[j] = (bf16)0.f; }
  if (l > 0)      lf = *(const bf16x8*)(p - DM);
  if (l < SL - 1) rt = *(const bf16x8*)(p + DM);
  bf16x8 o;
#pragma unroll
  for (int j = 0; j < 8; ++j) {
    const int d = d0 + j;
    float y = cw[d * 3 + 0] * (float)lf[j] + cw[d * 3 + 1] * (float)cc[j]
            + cw[d * 3 + 2] * (float)rt[j] + cb[d];
    y = y / (1.f + __expf(-y));
    o[j] = (bf16)y;
  }
  *(bf16x8*)(xc + (size_t)bl * DM + d0) = o;
}

// ===========================================================================
// Parallel scan over L, 3 phases, chunked (LC=256, NC=16).
// ===========================================================================
__global__ void scan_phase1(bf16* nla_sl, const bf16* __restrict__ bx,
                            float* __restrict__ Lp_tot, float* __restrict__ T_tot) {
  const int g  = blockIdx.x * 256 + threadIdx.x;
  const int ch = g & (DH - 1);
  const int rc = g >> 11;
  const int b  = rc & (NB - 1);
  const int c  = rc >> 2;
  const int bc = b * DH + ch;
  size_t off = ((size_t)(b * SL + c * LC)) * DH + ch;
  float lp = 0.f, S = 0.f;
#pragma unroll 8
  for (int l = 0; l < LC; ++l, off += DH) {
    const float a = (float)nla_sl[off];
    const float x = (float)bx[off];
    lp += a;
    const float e = __expf(-fminf(fmaxf(lp, -80.f), 80.f));
    S = fmaf(x, e, S);
    nla_sl[off] = (bf16)S;
  }
  Lp_tot[c * (NB * DH) + bc] = lp;
  T_tot [c * (NB * DH) + bc] = S;
}

__global__ void scan_phase2(const float* __restrict__ Lp_tot, const float* __restrict__ T_tot,
                            float* __restrict__ lpoff, float* __restrict__ Soff) {
  const int bc = blockIdx.x * 256 + threadIdx.x;
  float lp = 0.f, S = 0.f;
#pragma unroll
  for (int c = 0; c < NC; ++c) {
    lpoff[c * (NB * DH) + bc] = lp;
    Soff [c * (NB * DH) + bc] = S;
    const float e = __expf(-fminf(fmaxf(lp, -80.f), 80.f));
    S  = fmaf(e, T_tot[c * (NB * DH) + bc], S);
    lp += Lp_tot[c * (NB * DH) + bc];
  }
}

__global__ void scan_phase3(const bf16* __restrict__ S_local, bf16* __restrict__ h,
                            const float* __restrict__ lpoff, const float* __restrict__ Soff) {
  const int g  = blockIdx.x * 256 + threadIdx.x;
  const int ch = g & (DH - 1);
  const int rc = g >> 11;
  const int b  = rc & (NB - 1);
  const int c  = rc >> 2;
  const int bc = b * DH + ch;
  const float lo = lpoff[c * (NB * DH) + bc];
  const float so = Soff [c * (NB * DH) + bc];
  const float es = __expf(-fminf(fmaxf(lo, -80.f), 80.f));
  size_t off = ((size_t)(b * SL + c * LC)) * DH + ch;
#pragma unroll 8
  for (int l = 0; l < LC; ++l, off += DH) {
    h[off] = (bf16)fmaf(es, (float)S_local[off], so);
  }
}

// ===========================================================================
// Workspace (max live 186 MB), offsets in MB:
//  [  0.. 24): bf16 weights (persistent)
//  [ 24.. 56): xc
//  [ 56..120): t1 [56,88) / xbf [88,120) -> bxh (Bx, then h) ; z [56,88)
//  [120..184): nla (scan in-place) -> ssm [120,152)
//  [184..186): scan totals
// ===========================================================================
extern "C" void kernel_launch(void* const* d_in, const int* in_sizes, int n_in,
                              void* d_out, int out_size, void* d_ws, size_t ws_size,
                              hipStream_t stream) {
  const float* x    = (const float*)d_in[0];
  const float* w1   = (const float*)d_in[1];
  const float* w2   = (const float*)d_in[2];
  const float* w3   = (const float*)d_in[3];
  const float* cw   = (const float*)d_in[4];
  const float* cb   = (const float*)d_in[5];
  const float* A_w  = (const float*)d_in[6];
  const float* A_b  = (const float*)d_in[7];
  const float* B_w  = (const float*)d_in[8];
  const float* B_b  = (const float*)d_in[9];
  const float* C_w  = (const float*)d_in[10];
  const float* C_b  = (const float*)d_in[11];
  const float* D_w  = (const float*)d_in[12];
  const float* D_b  = (const float*)d_in[13];
  const float* dl_w = (const float*)d_in[14];
  const float* dl_b = (const float*)d_in[15];

  const size_t MB = 1048576u;
  char* ws = (char*)d_ws;
  bf16* w1b  = (bf16*)(ws + 0*MB);
  bf16* w2b  = (bf16*)(ws + 2*MB);
  bf16* w3b  = (bf16*)(ws + 4*MB);
  bf16* Dwb  = (bf16*)(ws + 6*MB);
  bf16* Awb  = (bf16*)(ws + 8*MB);
  bf16* Bwb  = (bf16*)(ws + 12*MB);
  bf16* dlwb = (bf16*)(ws + 16*MB);
  bf16* Cwb  = (bf16*)(ws + 20*MB);
  bf16* xc   = (bf16*)(ws + 24*MB);
  bf16* t1   = (bf16*)(ws + 56*MB);
  bf16* z    = t1;
  bf16* xbf  = (bf16*)(ws + 88*MB);
  bf16* bxh  = (bf16*)(ws + 56*MB);   // 64 MB: Bx, then h (phase3 in-place)
  bf16* nla  = (bf16*)(ws + 120*MB);  // 64 MB; S_local in-place
  bf16* ssm  = (bf16*)(ws + 120*MB);  // 32 MB, after nla dies (post-scan3)
  float* Lp_tot = (float*)(ws + 184*MB);
  float* T_tot  = (float*)(ws + 184*MB + 524288u);
  float* lpoff  = (float*)(ws + 185*MB);
  float* Soff   = (float*)(ws + 185*MB + 524288u);
  float* outp = (float*)d_out;

  dim3 blk(256);
  dim3 blk512(512);
  dim3 g1_256(DM / 256, MT / 256);   // (4, 64)
  dim3 g2_256(DH / 256, MT / 256);   // (8, 64)
  dim3 g2(DH / 128, MT / 128);       // dual: (16, 128)

  // --- convert all inputs to bf16 (sanitizing), single launch ---
  {
    CvtArgs a;
    const float* ins[9]  = {x, w1, w2, w3, D_w, A_w, B_w, dl_w, C_w};
    bf16*        outs[9] = {xbf, w1b, w2b, w3b, Dwb, Awb, Bwb, dlwb, Cwb};
    const int    n4s[9]  = {MT*DM/4, DM*DM/4, DM*DM/4, DM*DM/4, DM*DM/4,
                            DH*DM/4, DH*DM/4, DH*DM/4, DM*DH/4};
    int c = 0;
    a.cum[0] = 0;
    for (int i = 0; i < 9; ++i) { a.in[i] = ins[i]; a.out[i] = outs[i]; c += n4s[i]; a.cum[i+1] = c; }
    cvt_all<<<2048, blk, 0, stream>>>(a);
  }

  // --- pipeline ---
  gemm256<0,false,DM,DM,0><<<g1_256, blk512, 0, stream>>>(xbf, w1b, nullptr,
      nullptr, nullptr, nullptr, nullptr, t1);
  conv_silu_kernel<<<MT * DM / 8 / 256, blk, 0, stream>>>(t1, cw, cb, xc);
  gemm_dual<DH,DM><<<g2, blk, 0, stream>>>(xc, dlwb, Awb, dl_b, A_b, nla);
  gemm256<0,true ,DH,DM,0><<<g2_256, blk512, 0, stream>>>(xc, Bwb, B_b,
      nullptr, nullptr, nullptr, nullptr, bxh);
  scan_phase1<<<MT * NC * DH / SL / 256, blk, 0, stream>>>(nla, bxh, Lp_tot, T_tot);
  scan_phase2<<<NB * DH / 256, blk, 0, stream>>>(Lp_tot, T_tot, lpoff, Soff);
  scan_phase3<<<MT * NC * DH / SL / 256, blk, 0, stream>>>(nla, bxh, lpoff, Soff);
  // ssm = C.h + D.x + C_b + D_b  (concatenated-K fused pass)
  gemm256<0,true ,DM,DH,DM><<<g1_256, blk512, 0, stream>>>(bxh, Cwb, C_b,
      xc, Dwb, D_b, nullptr, ssm);
  gemm256<2,false,DM,DM,0><<<g1_256, blk512, 0, stream>>>(ssm, w2b, nullptr,
      nullptr, nullptr, nullptr, ssm, z);
  gemm256<1,false,DM,DM,0><<<g1_256, blk512, 0, stream>>>(z,   w3b, nullptr,
      nullptr, nullptr, nullptr, ssm, outp);
}